// Round 3
// baseline (650.791 us; speedup 1.0000x reference)
//
#include <hip/hip_runtime.h>

#define BB 64
#define NN 512
#define FF 4
#define INC 64
#define HC 128
#define OUTC 16
#define KK (NN * FF)  // 2048
#define LDA 72        // padded LDS row (bf16 elements) for 64-el tiles
#define BK 64

typedef short short8 __attribute__((ext_vector_type(8)));
typedef float f32x4 __attribute__((ext_vector_type(4)));

__device__ __forceinline__ unsigned short f2bf(float x) {
  union { float f; unsigned u; } v;
  v.f = x;
  unsigned r = v.u + 0x7fffu + ((v.u >> 16) & 1u);  // round-to-nearest-even
  return (unsigned short)(r >> 16);
}

__device__ __forceinline__ float silu_f(float x) {
  return x * (1.0f / (1.0f + __expf(-x)));
}

// ---------------------------------------------------------------------------
// Kernel 1 (prep): one wave per (b,i) row.
//   deg[b,i,f]  = rsqrt(max(rowsum(adjhat),1))      (adjhat: diag->1)
//   Ap[b,i,k]   = bf16( deg_i[f] * adjhat[i,(j,f)] )  (deg_j folded into Hs)
// Reads adj once (256 MB), writes Ap (128 MB bf16) + deg (512 KB).
// ---------------------------------------------------------------------------
__global__ __launch_bounds__(256) void prep_kernel(
    const float* __restrict__ adj, float* __restrict__ deg,
    unsigned short* __restrict__ Ap) {
  int wave = blockIdx.x * 4 + (threadIdx.x >> 6);
  int lane = threadIdx.x & 63;
  int b = wave >> 9;
  int i = wave & (NN - 1);
  const float4* row = (const float4*)(adj) + (size_t)(b * NN + i) * NN;
  float4 rv[8];
  float4 s = make_float4(0.f, 0.f, 0.f, 0.f);
#pragma unroll
  for (int jj = 0; jj < 8; ++jj) {
    float4 v = row[jj * 64 + lane];
    if (jj * 64 + lane == i) v = make_float4(1.f, 1.f, 1.f, 1.f);  // diag->1
    rv[jj] = v;
    s.x += v.x; s.y += v.y; s.z += v.z; s.w += v.w;
  }
#pragma unroll
  for (int off = 32; off >= 1; off >>= 1) {
    s.x += __shfl_xor(s.x, off);
    s.y += __shfl_xor(s.y, off);
    s.z += __shfl_xor(s.z, off);
    s.w += __shfl_xor(s.w, off);
  }
  float4 d;
  d.x = rsqrtf(fmaxf(s.x, 1.0f));
  d.y = rsqrtf(fmaxf(s.y, 1.0f));
  d.z = rsqrtf(fmaxf(s.z, 1.0f));
  d.w = rsqrtf(fmaxf(s.w, 1.0f));
  unsigned short* arow = Ap + (size_t)(b * NN + i) * KK;
#pragma unroll
  for (int jj = 0; jj < 8; ++jj) {
    ushort4 o;
    o.x = f2bf(rv[jj].x * d.x);
    o.y = f2bf(rv[jj].y * d.y);
    o.z = f2bf(rv[jj].z * d.z);
    o.w = f2bf(rv[jj].w * d.w);
    *(ushort4*)&arow[(jj * 64 + lane) * 4] = o;
  }
  if (lane == 0) ((float4*)deg)[b * NN + i] = d;
}

// ---------------------------------------------------------------------------
// Kernel 2: Hs_T[b, c, j*4+f] = deg[b,j,f] * (xin[b,j,:] @ W[:,c])   (bf16)
// deg_j folded HERE; Ap carries deg_i. Stored c-major for agg B-fragments.
// ---------------------------------------------------------------------------
__global__ __launch_bounds__(256) void lin_hs_kernel(
    const float* __restrict__ xin, const float* __restrict__ W,
    const float* __restrict__ deg, unsigned short* __restrict__ Hs, int CIN) {
  __shared__ float xt[16 * HC];
  int b = blockIdx.y;
  int j0 = blockIdx.x * 16;
  int t = threadIdx.x;
  for (int idx = t; idx < 16 * CIN; idx += 256)
    xt[idx] = xin[(size_t)(b * NN + j0) * CIN + idx];
  __syncthreads();

  int c = t & (HC - 1);
  int gg = t >> 7;
  float acc[8];
#pragma unroll
  for (int jj = 0; jj < 8; ++jj) acc[jj] = 0.f;
  const float* xrow = &xt[gg * 8 * CIN];
  for (int k = 0; k < CIN; k += 4) {
    float w0 = W[(k + 0) * HC + c];
    float w1 = W[(k + 1) * HC + c];
    float w2 = W[(k + 2) * HC + c];
    float w3 = W[(k + 3) * HC + c];
#pragma unroll
    for (int jj = 0; jj < 8; ++jj) {
      float4 x4 = *(const float4*)&xrow[jj * CIN + k];
      acc[jj] = fmaf(x4.x, w0, acc[jj]);
      acc[jj] = fmaf(x4.y, w1, acc[jj]);
      acc[jj] = fmaf(x4.z, w2, acc[jj]);
      acc[jj] = fmaf(x4.w, w3, acc[jj]);
    }
  }
#pragma unroll
  for (int jj = 0; jj < 8; ++jj) {
    int j = j0 + gg * 8 + jj;
    float4 d4 = ((const float4*)deg)[b * NN + j];
    ushort4 o;
    o.x = f2bf(acc[jj] * d4.x);
    o.y = f2bf(acc[jj] * d4.y);
    o.z = f2bf(acc[jj] * d4.z);
    o.w = f2bf(acc[jj] * d4.w);
    *(ushort4*)&Hs[(size_t)(b * HC + c) * KK + 4 * j] = o;
  }
}

// ---------------------------------------------------------------------------
// Kernel 3: out[b,i,c] = silu(Sum_k Ap[i,k]*Hs[k,c] + bias) * mask
// Pure bf16 GEMM, 64(i) x 128(c) tile, BK=64, register-prefetch pipeline.
// grid = (BB, NN/64): all 8 i-tiles of a batch share an XCD (Hs L2 reuse).
// mode 0: store hout.  mode 1: mean-pool into g.
// ---------------------------------------------------------------------------
__global__ __launch_bounds__(256) void agg_kernel(
    const unsigned short* __restrict__ Ap, const unsigned short* __restrict__ Hs,
    const float* __restrict__ bias, const int* __restrict__ mask,
    float* __restrict__ hout, float* __restrict__ g, int mode) {
  __shared__ float smask[64];
  __shared__ float spool[HC];
  __shared__ unsigned short sA[64 * LDA];   // 9.2 KB
  __shared__ unsigned short sB[HC * LDA];   // 18.4 KB

  int b = blockIdx.x;
  int i0 = blockIdx.y * 64;
  int t = threadIdx.x;
  int lane = t & 63, w = t >> 6;
  int wm = w >> 1, wn = w & 1;
  int lm = lane & 15, lk = lane >> 4;

  if (t < 64) smask[t] = (float)mask[b * NN + i0 + t];
  if (t < HC) spool[t] = 0.f;

  // staging coords
  int ar = t >> 3, ac = t & 7;    // A: rows ar, ar+32; 16B chunk ac
  int br = t >> 1, bs = t & 1;    // B: row br; 64B seg bs
  const unsigned short* ApB = Ap + (size_t)(b * NN + i0) * KK;
  const unsigned short* HsB = Hs + (size_t)b * HC * KK;

  f32x4 acc[2][4];
#pragma unroll
  for (int mt = 0; mt < 2; ++mt)
#pragma unroll
    for (int nt = 0; nt < 4; ++nt) acc[mt][nt] = (f32x4){0.f, 0.f, 0.f, 0.f};

  // prefetch tile 0
  float4 pa0, pa1, pb[4];
  pa0 = *(const float4*)&ApB[(size_t)ar * KK + ac * 8];
  pa1 = *(const float4*)&ApB[(size_t)(ar + 32) * KK + ac * 8];
#pragma unroll
  for (int p = 0; p < 4; ++p)
    pb[p] = *(const float4*)&HsB[(size_t)br * KK + bs * 32 + p * 8];

  for (int k0 = 0; k0 < KK; k0 += BK) {
    // stage prefetched regs -> LDS
    *(float4*)&sA[ar * LDA + ac * 8] = pa0;
    *(float4*)&sA[(ar + 32) * LDA + ac * 8] = pa1;
#pragma unroll
    for (int p = 0; p < 4; ++p)
      *(float4*)&sB[br * LDA + bs * 32 + p * 8] = pb[p];
    __syncthreads();

    // issue next tile's global loads (overlap with MFMA below)
    if (k0 + BK < KK) {
      int kn = k0 + BK;
      pa0 = *(const float4*)&ApB[(size_t)ar * KK + kn + ac * 8];
      pa1 = *(const float4*)&ApB[(size_t)(ar + 32) * KK + kn + ac * 8];
#pragma unroll
      for (int p = 0; p < 4; ++p)
        pb[p] = *(const float4*)&HsB[(size_t)br * KK + kn + bs * 32 + p * 8];
    }

#pragma unroll
    for (int kk = 0; kk < 2; ++kk) {
      short8 aF[2], bF[4];
#pragma unroll
      for (int mt = 0; mt < 2; ++mt)
        aF[mt] = *(const short8*)&sA[(wm * 32 + mt * 16 + lm) * LDA + kk * 32 + lk * 8];
#pragma unroll
      for (int nt = 0; nt < 4; ++nt)
        bF[nt] = *(const short8*)&sB[(wn * 64 + nt * 16 + lm) * LDA + kk * 32 + lk * 8];
#pragma unroll
      for (int mt = 0; mt < 2; ++mt)
#pragma unroll
        for (int nt = 0; nt < 4; ++nt)
          acc[mt][nt] = __builtin_amdgcn_mfma_f32_16x16x32_bf16(
              aF[mt], bF[nt], acc[mt][nt], 0, 0, 0);
    }
    __syncthreads();
  }

  // epilogue: C/D layout row=(lane>>4)*4+r, col=lane&15 (m89/m91)
  if (mode == 0) {
#pragma unroll
    for (int mt = 0; mt < 2; ++mt) {
#pragma unroll
      for (int r = 0; r < 4; ++r) {
        int row = wm * 32 + mt * 16 + lk * 4 + r;
        float mk = smask[row];
        size_t base = (size_t)(b * NN + i0 + row) * HC;
#pragma unroll
        for (int nt = 0; nt < 4; ++nt) {
          int col = wn * 64 + nt * 16 + lm;
          hout[base + col] = silu_f(acc[mt][nt][r] + bias[col]) * mk;
        }
      }
    }
  } else {
    float psum[4] = {0.f, 0.f, 0.f, 0.f};
#pragma unroll
    for (int mt = 0; mt < 2; ++mt)
#pragma unroll
      for (int r = 0; r < 4; ++r) {
        int row = wm * 32 + mt * 16 + lk * 4 + r;
        float mk = smask[row];
#pragma unroll
        for (int nt = 0; nt < 4; ++nt) {
          int col = wn * 64 + nt * 16 + lm;
          psum[nt] += silu_f(acc[mt][nt][r] + bias[col]) * mk;
        }
      }
#pragma unroll
    for (int nt = 0; nt < 4; ++nt)
      atomicAdd(&spool[wn * 64 + nt * 16 + lm], psum[nt]);
    __syncthreads();
    if (t < HC) atomicAdd(&g[b * HC + t], spool[t] * (1.0f / (float)NN));
  }
}

// ---------------------------------------------------------------------------
// Kernel 4: g -> silu(g@Wl1+bl1) -> @Wl2+bl2. One block (128 thr) per batch.
// ---------------------------------------------------------------------------
__global__ __launch_bounds__(128) void mlp_kernel(
    const float* __restrict__ g, const float* __restrict__ Wl1,
    const float* __restrict__ bl1, const float* __restrict__ Wl2,
    const float* __restrict__ bl2, float* __restrict__ out) {
  __shared__ float sg[HC];
  __shared__ float sh[HC];
  int b = blockIdx.x, t = threadIdx.x;
  sg[t] = g[b * HC + t];
  __syncthreads();
  float acc = bl1[t];
  for (int k = 0; k < HC; ++k) acc = fmaf(sg[k], Wl1[k * HC + t], acc);
  sh[t] = silu_f(acc);
  __syncthreads();
  if (t < OUTC) {
    float a2 = bl2[t];
    for (int k = 0; k < HC; ++k) a2 = fmaf(sh[k], Wl2[k * OUTC + t], a2);
    out[b * OUTC + t] = a2;
  }
}

extern "C" void kernel_launch(void* const* d_in, const int* in_sizes, int n_in,
                              void* d_out, int out_size, void* d_ws,
                              size_t ws_size, hipStream_t stream) {
  const float* x   = (const float*)d_in[0];
  const float* adj = (const float*)d_in[1];
  const int*   msk = (const int*)d_in[2];
  const float* W0  = (const float*)d_in[3];
  const float* b0  = (const float*)d_in[4];
  const float* W1  = (const float*)d_in[5];
  const float* b1  = (const float*)d_in[6];
  const float* Wl1 = (const float*)d_in[7];
  const float* bl1 = (const float*)d_in[8];
  const float* Wl2 = (const float*)d_in[9];
  const float* bl2 = (const float*)d_in[10];
  float* out = (float*)d_out;

  // workspace layout (~177 MB)
  char* ws = (char*)d_ws;
  float* deg = (float*)ws;                                  // 512 KB
  unsigned short* Hs = (unsigned short*)(ws + (1u << 19));  // 32 MB
  unsigned short* Ap = (unsigned short*)(ws + (1u << 19) + (1u << 25));  // 128 MB
  float* h1 = (float*)(ws + (1u << 19) + (1u << 25) + (1u << 27));       // 16 MB
  float* g  = (float*)(ws + (1u << 19) + (1u << 25) + (1u << 27) + (1u << 24));

  hipMemsetAsync(g, 0, BB * HC * sizeof(float), stream);
  prep_kernel<<<BB * NN / 4, 256, 0, stream>>>(adj, deg, Ap);
  lin_hs_kernel<<<dim3(NN / 16, BB), 256, 0, stream>>>(x, W0, deg, Hs, INC);
  agg_kernel<<<dim3(BB, NN / 64), 256, 0, stream>>>(Ap, Hs, b0, msk, h1,
                                                    nullptr, 0);
  lin_hs_kernel<<<dim3(NN / 16, BB), 256, 0, stream>>>(h1, W1, deg, Hs, HC);
  agg_kernel<<<dim3(BB, NN / 64), 256, 0, stream>>>(Ap, Hs, b1, msk, nullptr,
                                                    g, 1);
  mlp_kernel<<<BB, HC, 0, stream>>>(g, Wl1, bl1, Wl2, bl2, out);
}

// Round 4
// 533.912 us; speedup vs baseline: 1.2189x; 1.2189x over previous
//
#include <hip/hip_runtime.h>

#define BB 64
#define NN 512
#define FF 4
#define INC 64
#define HC 128
#define OUTC 16
#define KK 2048
#define NKT 32  // K-tiles of 64

// Ap layout: [b][kt][i(512)][64 k-els]  bf16, 16B granules XOR-swizzled by (i&7)
// Hs layout: [b][kt][c(128)][64 k-els]  bf16, granules XOR-swizzled by (c&7)

typedef short short8 __attribute__((ext_vector_type(8)));
typedef float f32x4 __attribute__((ext_vector_type(4)));

__device__ __forceinline__ unsigned short f2bf(float x) {
  union { float f; unsigned u; } v;
  v.f = x;
  unsigned r = v.u + 0x7fffu + ((v.u >> 16) & 1u);  // RNE
  return (unsigned short)(r >> 16);
}

__device__ __forceinline__ float silu_f(float x) {
  return x * (1.0f / (1.0f + __expf(-x)));
}

// async global->LDS, 16B per lane; lptr must be wave-uniform (HW adds lane*16)
__device__ __forceinline__ void glds16(const void* g, void* l) {
  __builtin_amdgcn_global_load_lds(
      (const __attribute__((address_space(1))) void*)g,
      (__attribute__((address_space(3))) void*)l, 16, 0, 0);
}

// ---------------------------------------------------------------------------
// Kernel 1 (prep): one wave per (b,i) row.
//   deg[b,i,f] = rsqrt(max(rowsum(adjhat),1))   (adjhat: diag->1)
//   Ap[b][kt][i][:] = bf16(deg_i[f] * adjhat), swizzled granules
// ---------------------------------------------------------------------------
__global__ __launch_bounds__(256) void prep_kernel(
    const float* __restrict__ adj, float* __restrict__ deg,
    unsigned short* __restrict__ Ap) {
  int wave = blockIdx.x * 4 + (threadIdx.x >> 6);
  int lane = threadIdx.x & 63;
  int b = wave >> 9;
  int i = wave & (NN - 1);
  const float4* row = (const float4*)(adj) + (size_t)(b * NN + i) * NN;
  float4 rv[8];
  float4 s = make_float4(0.f, 0.f, 0.f, 0.f);
#pragma unroll
  for (int jj = 0; jj < 8; ++jj) {
    float4 v = row[jj * 64 + lane];
    if (jj * 64 + lane == i) v = make_float4(1.f, 1.f, 1.f, 1.f);  // diag->1
    rv[jj] = v;
    s.x += v.x; s.y += v.y; s.z += v.z; s.w += v.w;
  }
#pragma unroll
  for (int off = 32; off >= 1; off >>= 1) {
    s.x += __shfl_xor(s.x, off);
    s.y += __shfl_xor(s.y, off);
    s.z += __shfl_xor(s.z, off);
    s.w += __shfl_xor(s.w, off);
  }
  float4 d;
  d.x = rsqrtf(fmaxf(s.x, 1.0f));
  d.y = rsqrtf(fmaxf(s.y, 1.0f));
  d.z = rsqrtf(fmaxf(s.z, 1.0f));
  d.w = rsqrtf(fmaxf(s.w, 1.0f));
  int sw = i & 7;
  int pos = ((lane >> 1) & 7) ^ sw;        // swizzled 16B-granule within row
  int half = lane & 1;                     // 8B half of the granule
#pragma unroll
  for (int jj = 0; jj < 8; ++jj) {
    int kt = jj * 4 + (lane >> 4);
    size_t base = ((size_t)(b * NKT + kt) * NN + i) * 64;
    ushort4 o;
    o.x = f2bf(rv[jj].x * d.x);
    o.y = f2bf(rv[jj].y * d.y);
    o.z = f2bf(rv[jj].z * d.z);
    o.w = f2bf(rv[jj].w * d.w);
    *(ushort4*)&Ap[base + pos * 8 + half * 4] = o;
  }
  if (lane == 0) ((float4*)deg)[b * NN + i] = d;
}

// ---------------------------------------------------------------------------
// Kernel 2: Hs[b][kt][c][k] = deg[b,j,f] * (xin[b,j,:] @ W[:,c])  (bf16)
// Each block covers exactly one kt (16 j-rows). deg_j folded here.
// ---------------------------------------------------------------------------
__global__ __launch_bounds__(256) void lin_hs_kernel(
    const float* __restrict__ xin, const float* __restrict__ W,
    const float* __restrict__ deg, unsigned short* __restrict__ Hs, int CIN) {
  __shared__ float xt[16 * HC];
  int b = blockIdx.y;
  int kt = blockIdx.x;
  int j0 = kt * 16;
  int t = threadIdx.x;
  for (int idx = t; idx < 16 * CIN; idx += 256)
    xt[idx] = xin[(size_t)(b * NN + j0) * CIN + idx];
  __syncthreads();

  int c = t & (HC - 1);
  int gg = t >> 7;  // 0..1 -> 8 j-rows each
  float acc[8];
#pragma unroll
  for (int jj = 0; jj < 8; ++jj) acc[jj] = 0.f;
  const float* xrow = &xt[gg * 8 * CIN];
  for (int k = 0; k < CIN; k += 4) {
    float w0 = W[(k + 0) * HC + c];
    float w1 = W[(k + 1) * HC + c];
    float w2 = W[(k + 2) * HC + c];
    float w3 = W[(k + 3) * HC + c];
#pragma unroll
    for (int jj = 0; jj < 8; ++jj) {
      float4 x4 = *(const float4*)&xrow[jj * CIN + k];
      acc[jj] = fmaf(x4.x, w0, acc[jj]);
      acc[jj] = fmaf(x4.y, w1, acc[jj]);
      acc[jj] = fmaf(x4.z, w2, acc[jj]);
      acc[jj] = fmaf(x4.w, w3, acc[jj]);
    }
  }
  int sw = c & 7;
  size_t base = ((size_t)(b * NKT + kt) * HC + c) * 64;
#pragma unroll
  for (int u = 0; u < 4; ++u) {
    int ja = j0 + gg * 8 + 2 * u;
    float4 da = ((const float4*)deg)[b * NN + ja];
    float4 db = ((const float4*)deg)[b * NN + ja + 1];
    short8 o;
    o[0] = (short)f2bf(acc[2 * u] * da.x);
    o[1] = (short)f2bf(acc[2 * u] * da.y);
    o[2] = (short)f2bf(acc[2 * u] * da.z);
    o[3] = (short)f2bf(acc[2 * u] * da.w);
    o[4] = (short)f2bf(acc[2 * u + 1] * db.x);
    o[5] = (short)f2bf(acc[2 * u + 1] * db.y);
    o[6] = (short)f2bf(acc[2 * u + 1] * db.z);
    o[7] = (short)f2bf(acc[2 * u + 1] * db.w);
    int pos = (gg * 4 + u) ^ sw;
    *(short8*)&Hs[base + pos * 8] = o;
  }
}

// ---------------------------------------------------------------------------
// Kernel 3: out[b,i,c] = silu(Sum_k Ap[i,k]*Hs[k,c] + bias) * mask
// 64(i) x 128(c) tile, BK=64, m97 2-barrier K-loop, global_load_lds staging.
// Per iter: A = 8 KB contiguous, B = 16 KB contiguous (kt-major layout).
// grid (BB, 8): all 8 i-tiles of batch b land on XCD b%8 (Hs L2 reuse).
// mode 0: store hout.  mode 1: mean-pool into g.
// ---------------------------------------------------------------------------
__global__ __launch_bounds__(256) void agg_kernel(
    const unsigned short* __restrict__ Ap, const unsigned short* __restrict__ Hs,
    const float* __restrict__ bias, const int* __restrict__ mask,
    float* __restrict__ hout, float* __restrict__ g, int mode) {
  __shared__ unsigned short sA[64 * 64];   // 8 KB, swizzled rows
  __shared__ unsigned short sB[128 * 64];  // 16 KB, swizzled rows
  __shared__ float smask[64];
  __shared__ float spool[HC];

  int b = blockIdx.x;
  int i0 = blockIdx.y * 64;
  int t = threadIdx.x;
  int lane = t & 63, w = t >> 6;
  int wm = w >> 1, wn = w & 1;
  int lm = lane & 15, lk = lane >> 4;

  if (t < 64) smask[t] = (float)mask[b * NN + i0 + t];
  if (t < HC) spool[t] = 0.f;

  const char* Apb = (const char*)(Ap + ((size_t)b * NKT * NN + i0) * 64);
  const char* Hsb = (const char*)(Hs + (size_t)b * NKT * HC * 64);
  char* sAb = (char*)sA;
  char* sBb = (char*)sB;

  f32x4 acc[2][4];
#pragma unroll
  for (int mt = 0; mt < 2; ++mt)
#pragma unroll
    for (int nt = 0; nt < 4; ++nt) acc[mt][nt] = (f32x4){0.f, 0.f, 0.f, 0.f};

  for (int kt = 0; kt < NKT; ++kt) {
    const char* At = Apb + (size_t)kt * NN * 128;  // this block's 8 KB A tile
    const char* Bt = Hsb + (size_t)kt * HC * 128;  // this batch's 16 KB B tile
#pragma unroll
    for (int p = 0; p < 2; ++p)
      glds16(At + p * 4096 + t * 16, sAb + p * 4096 + w * 1024);
#pragma unroll
    for (int p = 0; p < 4; ++p)
      glds16(Bt + p * 4096 + t * 16, sBb + p * 4096 + w * 1024);
    __syncthreads();  // drains vmcnt (glds counted there)

#pragma unroll
    for (int kk = 0; kk < 2; ++kk) {
      short8 aF[2], bF[4];
#pragma unroll
      for (int mt = 0; mt < 2; ++mt) {
        int r = wm * 32 + mt * 16 + lm;
        int pos = (kk * 4 + lk) ^ (r & 7);
        aF[mt] = *(const short8*)&sA[r * 64 + pos * 8];
      }
#pragma unroll
      for (int nt = 0; nt < 4; ++nt) {
        int r = wn * 64 + nt * 16 + lm;
        int pos = (kk * 4 + lk) ^ (r & 7);
        bF[nt] = *(const short8*)&sB[r * 64 + pos * 8];
      }
#pragma unroll
      for (int mt = 0; mt < 2; ++mt)
#pragma unroll
        for (int nt = 0; nt < 4; ++nt)
          acc[mt][nt] = __builtin_amdgcn_mfma_f32_16x16x32_bf16(
              aF[mt], bF[nt], acc[mt][nt], 0, 0, 0);
    }
    __syncthreads();
  }

  // epilogue: C/D layout row=(lane>>4)*4+r, col=lane&15 (m89/m91)
  if (mode == 0) {
#pragma unroll
    for (int mt = 0; mt < 2; ++mt) {
#pragma unroll
      for (int r = 0; r < 4; ++r) {
        int row = wm * 32 + mt * 16 + lk * 4 + r;
        float mk = smask[row];
        size_t base = (size_t)(b * NN + i0 + row) * HC;
#pragma unroll
        for (int nt = 0; nt < 4; ++nt) {
          int col = wn * 64 + nt * 16 + lm;
          hout[base + col] = silu_f(acc[mt][nt][r] + bias[col]) * mk;
        }
      }
    }
  } else {
    float psum[4] = {0.f, 0.f, 0.f, 0.f};
#pragma unroll
    for (int mt = 0; mt < 2; ++mt)
#pragma unroll
      for (int r = 0; r < 4; ++r) {
        int row = wm * 32 + mt * 16 + lk * 4 + r;
        float mk = smask[row];
#pragma unroll
        for (int nt = 0; nt < 4; ++nt) {
          int col = wn * 64 + nt * 16 + lm;
          psum[nt] += silu_f(acc[mt][nt][r] + bias[col]) * mk;
        }
      }
#pragma unroll
    for (int nt = 0; nt < 4; ++nt)
      atomicAdd(&spool[wn * 64 + nt * 16 + lm], psum[nt]);
    __syncthreads();
    if (t < HC) atomicAdd(&g[b * HC + t], spool[t] * (1.0f / (float)NN));
  }
}

// ---------------------------------------------------------------------------
// Kernel 4: g -> silu(g@Wl1+bl1) -> @Wl2+bl2. One block (128 thr) per batch.
// ---------------------------------------------------------------------------
__global__ __launch_bounds__(128) void mlp_kernel(
    const float* __restrict__ g, const float* __restrict__ Wl1,
    const float* __restrict__ bl1, const float* __restrict__ Wl2,
    const float* __restrict__ bl2, float* __restrict__ out) {
  __shared__ float sg[HC];
  __shared__ float sh[HC];
  int b = blockIdx.x, t = threadIdx.x;
  sg[t] = g[b * HC + t];
  __syncthreads();
  float acc = bl1[t];
  for (int k = 0; k < HC; ++k) acc = fmaf(sg[k], Wl1[k * HC + t], acc);
  sh[t] = silu_f(acc);
  __syncthreads();
  if (t < OUTC) {
    float a2 = bl2[t];
    for (int k = 0; k < HC; ++k) a2 = fmaf(sh[k], Wl2[k * OUTC + t], a2);
    out[b * OUTC + t] = a2;
  }
}

extern "C" void kernel_launch(void* const* d_in, const int* in_sizes, int n_in,
                              void* d_out, int out_size, void* d_ws,
                              size_t ws_size, hipStream_t stream) {
  const float* x   = (const float*)d_in[0];
  const float* adj = (const float*)d_in[1];
  const int*   msk = (const int*)d_in[2];
  const float* W0  = (const float*)d_in[3];
  const float* b0  = (const float*)d_in[4];
  const float* W1  = (const float*)d_in[5];
  const float* b1  = (const float*)d_in[6];
  const float* Wl1 = (const float*)d_in[7];
  const float* bl1 = (const float*)d_in[8];
  const float* Wl2 = (const float*)d_in[9];
  const float* bl2 = (const float*)d_in[10];
  float* out = (float*)d_out;

  // workspace layout (~177 MB)
  char* ws = (char*)d_ws;
  float* deg = (float*)ws;                                  // 512 KB
  unsigned short* Hs = (unsigned short*)(ws + (1u << 19));  // 32 MB
  unsigned short* Ap = (unsigned short*)(ws + (1u << 19) + (1u << 25));  // 128 MB
  float* h1 = (float*)(ws + (1u << 19) + (1u << 25) + (1u << 27));       // 16 MB
  float* g  = (float*)(ws + (1u << 19) + (1u << 25) + (1u << 27) + (1u << 24));

  hipMemsetAsync(g, 0, BB * HC * sizeof(float), stream);
  prep_kernel<<<BB * NN / 4, 256, 0, stream>>>(adj, deg, Ap);
  lin_hs_kernel<<<dim3(NKT, BB), 256, 0, stream>>>(x, W0, deg, Hs, INC);
  agg_kernel<<<dim3(BB, NN / 64), 256, 0, stream>>>(Ap, Hs, b0, msk, h1,
                                                    nullptr, 0);
  lin_hs_kernel<<<dim3(NKT, BB), 256, 0, stream>>>(h1, W1, deg, Hs, HC);
  agg_kernel<<<dim3(BB, NN / 64), 256, 0, stream>>>(Ap, Hs, b1, msk, nullptr,
                                                    g, 1);
  mlp_kernel<<<BB, HC, 0, stream>>>(g, Wl1, bl1, Wl2, bl2, out);
}